// Round 2
// baseline (808.695 us; speedup 1.0000x reference)
//
#include <hip/hip_runtime.h>

#define NBATCH 16384
#define NBLK   4096     // grid size
#define NB     4        // batches per wave (NBLK*NB == NBATCH)
#define H 16
#define E 64

// One wave (64 threads) per block; each wave processes NB batches with
// software pipelining: next batch's global loads are issued after phase 2
// (post W-loads, pinned by sched_barrier) and consumed at next loop top,
// hiding HBM latency under phases 3-5 (LDS+VALU only).
__global__ __launch_bounds__(64, 3) void ovo_kernel(
    const float* __restrict__ o0, const float* __restrict__ o1,
    const float* __restrict__ o2, const float* __restrict__ o3,
    const float* __restrict__ mn, const float* __restrict__ W,
    float* __restrict__ ctx_out, float* __restrict__ attn_out)
{
    __shared__ float sM[H][68];     // m rows; overlaid with score/attn later
    __shared__ float sMain[H][68];  // main rows
    __shared__ float sMW[H][68];    // m @ W

    const int l   = threadIdx.x;
    const int bid = blockIdx.x;

    // prefetch registers (80 VGPRs in flight)
    float4 po0[4], po1[4], po2[4], po3[4], pmn[4];

    {   // prologue: issue loads for batch 0
        const size_t base = (size_t)bid * (H * E);
#pragma unroll
        for (int k = 0; k < 4; ++k) {
            const int flat = k * 256 + l * 4;
            po0[k] = *(const float4*)(o0 + base + flat);
            po1[k] = *(const float4*)(o1 + base + flat);
            po2[k] = *(const float4*)(o2 + base + flat);
            po3[k] = *(const float4*)(o3 + base + flat);
            pmn[k] = *(const float4*)(mn + base + flat);
        }
    }

#pragma unroll 1
    for (int it = 0; it < NB; ++it) {
        const int batch = it * NBLK + bid;

        // ---- Phase 1: combine prefetched regs -> mean in sM, main in sMain
#pragma unroll
        for (int k = 0; k < 4; ++k) {
            const int flat = k * 256 + l * 4;
            const int h = flat >> 6;
            const int e = flat & 63;
            float4 m4;
            m4.x = (po0[k].x + po1[k].x + po2[k].x + po3[k].x) * 0.25f;
            m4.y = (po0[k].y + po1[k].y + po2[k].y + po3[k].y) * 0.25f;
            m4.z = (po0[k].z + po1[k].z + po2[k].z + po3[k].z) * 0.25f;
            m4.w = (po0[k].w + po1[k].w + po2[k].w + po3[k].w) * 0.25f;
            *(float4*)&sM[h][e] = m4;
            *(float4*)&sMain[h][e] = pmn[k];
        }
        __syncthreads();

        // ---- Phase 2: mW[h][f] = sum_e m[h][e] * W[e][f]  (4x4 tile/lane)
        {
            const int ht = l >> 4, ft = l & 15;
            const int h0 = ht * 4, f0 = ft * 4;
            float acc[4][4] = {{0.f}};
#pragma unroll
            for (int e0 = 0; e0 < 64; e0 += 4) {
                float4 mrow[4], wrow[4];
#pragma unroll
                for (int i = 0; i < 4; ++i) mrow[i] = *(const float4*)&sM[h0 + i][e0];
#pragma unroll
                for (int j = 0; j < 4; ++j) wrow[j] = *(const float4*)&W[(e0 + j) * 64 + f0];
#pragma unroll
                for (int i = 0; i < 4; ++i) {
                    const float* mr = (const float*)&mrow[i];
#pragma unroll
                    for (int ee = 0; ee < 4; ++ee) {
                        const float* wr = (const float*)&wrow[ee];
#pragma unroll
                        for (int j = 0; j < 4; ++j)
                            acc[i][j] = fmaf(mr[ee], wr[j], acc[i][j]);
                    }
                }
            }
#pragma unroll
            for (int i = 0; i < 4; ++i)
                *(float4*)&sMW[h0 + i][f0] =
                    make_float4(acc[i][0], acc[i][1], acc[i][2], acc[i][3]);
        }
        __syncthreads();

        // ---- Prefetch next batch (pinned AFTER phase-2 W loads: vmcnt retires
        //      in order, so these must be the newest outstanding loads)
        __builtin_amdgcn_sched_barrier(0);
        if (it + 1 < NB) {
            const size_t nbase = (size_t)(batch + NBLK) * (H * E);
#pragma unroll
            for (int k = 0; k < 4; ++k) {
                const int flat = k * 256 + l * 4;
                po0[k] = *(const float4*)(o0 + nbase + flat);
                po1[k] = *(const float4*)(o1 + nbase + flat);
                po2[k] = *(const float4*)(o2 + nbase + flat);
                po3[k] = *(const float4*)(o3 + nbase + flat);
                pmn[k] = *(const float4*)(mn + nbase + flat);
            }
        }
        __builtin_amdgcn_sched_barrier(0);

        // ---- Phase 3: score[h][g] = sum_f mW[h][f]*main[g][f]
        //      writes into sM region (m no longer needed), stride 68
        {
            const int hp = l >> 3, gp = l & 7;
            const int h0 = hp * 2, g0 = gp * 2;
            float sc00 = 0.f, sc01 = 0.f, sc10 = 0.f, sc11 = 0.f;
#pragma unroll
            for (int f0 = 0; f0 < 64; f0 += 4) {
                float4 a0 = *(const float4*)&sMW[h0][f0];
                float4 a1 = *(const float4*)&sMW[h0 + 1][f0];
                float4 b0 = *(const float4*)&sMain[g0][f0];
                float4 b1 = *(const float4*)&sMain[g0 + 1][f0];
                const float* pa0 = (const float*)&a0;
                const float* pa1 = (const float*)&a1;
                const float* pb0 = (const float*)&b0;
                const float* pb1 = (const float*)&b1;
#pragma unroll
                for (int q = 0; q < 4; ++q) {
                    sc00 = fmaf(pa0[q], pb0[q], sc00);
                    sc01 = fmaf(pa0[q], pb1[q], sc01);
                    sc10 = fmaf(pa1[q], pb0[q], sc10);
                    sc11 = fmaf(pa1[q], pb1[q], sc11);
                }
            }
            *(float2*)&sM[h0][g0]     = make_float2(sc00, sc01);
            *(float2*)&sM[h0 + 1][g0] = make_float2(sc10, sc11);
        }
        __syncthreads();

        // ---- Phase 4: full-wave softmax. lane = h*4 + q, q owns 4 g's.
        {
            const int h = l >> 2, q = l & 3;
            float4 sc = *(const float4*)&sM[h][q * 4];
            float mx = fmaxf(fmaxf(sc.x, sc.y), fmaxf(sc.z, sc.w));
            mx = fmaxf(mx, __shfl_xor(mx, 1));
            mx = fmaxf(mx, __shfl_xor(mx, 2));
            float e0 = __expf(sc.x - mx), e1 = __expf(sc.y - mx);
            float e2 = __expf(sc.z - mx), e3 = __expf(sc.w - mx);
            float sum = (e0 + e1) + (e2 + e3);
            sum += __shfl_xor(sum, 1);
            sum += __shfl_xor(sum, 2);
            const float inv = 1.0f / sum;
            float4 a4 = make_float4(e0 * inv, e1 * inv, e2 * inv, e3 * inv);
            *(float4*)&sM[h][q * 4] = a4;   // in place: attn[h][g], stride 68
            // coalesced: lane l writes bytes [16l, 16l+16) of this batch's attn
            *(float4*)(attn_out + (size_t)batch * (H * H) + l * 4) = a4;
        }
        __syncthreads();

        // ---- Phase 5: context[h][e] = sum_g attn[h][g]*main[g][e] (4x4 tile)
        {
            const int ht = l >> 4, et = l & 15;
            const int h0 = ht * 4, e0c = et * 4;
            float acc[4][4] = {{0.f}};
#pragma unroll
            for (int g0 = 0; g0 < 16; g0 += 4) {
                float4 bv[4];
#pragma unroll
                for (int gg = 0; gg < 4; ++gg)
                    bv[gg] = *(const float4*)&sMain[g0 + gg][e0c];
#pragma unroll
                for (int i = 0; i < 4; ++i) {
                    float4 av = *(const float4*)&sM[h0 + i][g0];  // broadcast
                    const float* pa = (const float*)&av;
#pragma unroll
                    for (int gg = 0; gg < 4; ++gg) {
                        const float* pb = (const float*)&bv[gg];
#pragma unroll
                        for (int j = 0; j < 4; ++j)
                            acc[i][j] = fmaf(pa[gg], pb[j], acc[i][j]);
                    }
                }
            }
            float* cp = ctx_out + (size_t)batch * (H * E);
#pragma unroll
            for (int i = 0; i < 4; ++i)
                *(float4*)(cp + (h0 + i) * 64 + e0c) =
                    make_float4(acc[i][0], acc[i][1], acc[i][2], acc[i][3]);
        }
        __syncthreads();   // protect sM/sMain before next iteration's writes
    }
}

extern "C" void kernel_launch(void* const* d_in, const int* in_sizes, int n_in,
                              void* d_out, int out_size, void* d_ws, size_t ws_size,
                              hipStream_t stream) {
    const float* o0 = (const float*)d_in[0];
    const float* o1 = (const float*)d_in[1];
    const float* o2 = (const float*)d_in[2];
    const float* o3 = (const float*)d_in[3];
    const float* mn = (const float*)d_in[4];
    const float* W  = (const float*)d_in[5];
    float* ctx  = (float*)d_out;
    float* attn = ctx + (size_t)NBATCH * H * E;
    hipLaunchKernelGGL(ovo_kernel, dim3(NBLK), dim3(64), 0, stream,
                       o0, o1, o2, o3, mn, W, ctx, attn);
}

// Round 3
// 121.966 us; speedup vs baseline: 6.6305x; 6.6305x over previous
//
#include <hip/hip_runtime.h>

#define NBATCH 16384
#define NB     8
#define NBLK   (NBATCH / NB)   /* 2048 blocks */
#define H 16
#define E 64

// Fence macros. LGKM0: drain LDS ops at a phase boundary (cross-lane dep
// through LDS), then block scheduler motion (rule #18). VM0: drain the
// global_load_lds prefetch (+ stray stores) at loop top.
#define LGKM0 do { asm volatile("s_waitcnt lgkmcnt(0)" ::: "memory"); \
                   __builtin_amdgcn_sched_barrier(0); } while (0)
#define VM0   do { asm volatile("s_waitcnt vmcnt(0)" ::: "memory"); \
                   __builtin_amdgcn_sched_barrier(0); } while (0)

__device__ __forceinline__ void dma16(const float* gp, float* lp) {
    // 64 lanes x 16B: HW writes lds_base + lane*16; gp is per-lane.
    __builtin_amdgcn_global_load_lds(
        (const __attribute__((address_space(1))) void*)gp,
        (__attribute__((address_space(3))) void*)lp, 16, 0, 0);
}

// One wave (64 threads) per block, NB batches per wave, software-pipelined:
// next batch's 5 input tiles stream into LDS via global_load_lds while
// phases 3-5 (LDS+VALU only) compute the current batch. Single-wave blocks
// -> NO __syncthreads anywhere (s_barrier would force vmcnt(0) and drain
// the prefetch). Phase ordering via explicit lgkmcnt fences.
__global__ __launch_bounds__(64) void ovo_kernel(
    const float* __restrict__ o0, const float* __restrict__ o1,
    const float* __restrict__ o2, const float* __restrict__ o3,
    const float* __restrict__ mn, const float* __restrict__ W,
    float* __restrict__ ctx_out, float* __restrict__ attn_out)
{
    __shared__ float stg[5 * H * E];   // 20KB: o0|o1|o2|o3|main, linear tiles
    __shared__ float sMeanP[H][68];    // padded mean; overlaid score/attn after phase 2
    __shared__ float sMainP[H][68];    // padded main
    __shared__ float sMW[H][68];       // mean @ W

    const int l   = threadIdx.x;
    const int bid = blockIdx.x;

    // ---- prologue: issue DMA for batch 0
    {
        const size_t gbase = (size_t)(bid * NB) * (H * E);
#pragma unroll
        for (int k = 0; k < 4; ++k) {
            const int off = k * 256 + l * 4;
            dma16(o0 + gbase + off, &stg[0 * 1024 + k * 256]);
            dma16(o1 + gbase + off, &stg[1 * 1024 + k * 256]);
            dma16(o2 + gbase + off, &stg[2 * 1024 + k * 256]);
            dma16(o3 + gbase + off, &stg[3 * 1024 + k * 256]);
            dma16(mn + gbase + off, &stg[4 * 1024 + k * 256]);
        }
    }

#pragma unroll 1
    for (int it = 0; it < NB; ++it) {
        const int batch = bid * NB + it;

        VM0;   // staged tiles for this batch are now resident in LDS

        // ---- Phase 1: mean(others) -> sMeanP, main -> sMainP (padded)
#pragma unroll
        for (int k = 0; k < 4; ++k) {
            const int flat = k * 256 + l * 4;
            const int h = flat >> 6, e = flat & 63;
            float4 a = *(const float4*)&stg[0 * 1024 + flat];
            float4 b = *(const float4*)&stg[1 * 1024 + flat];
            float4 c = *(const float4*)&stg[2 * 1024 + flat];
            float4 d = *(const float4*)&stg[3 * 1024 + flat];
            float4 v = *(const float4*)&stg[4 * 1024 + flat];
            float4 m4;
            m4.x = (a.x + b.x + c.x + d.x) * 0.25f;
            m4.y = (a.y + b.y + c.y + d.y) * 0.25f;
            m4.z = (a.z + b.z + c.z + d.z) * 0.25f;
            m4.w = (a.w + b.w + c.w + d.w) * 0.25f;
            *(float4*)&sMeanP[h][e] = m4;
            *(float4*)&sMainP[h][e] = v;
        }
        LGKM0;

        // ---- Phase 2: mW[h][f] = sum_e mean[h][e]*W[e][f]  (4x4 tile/lane)
        {
            const int ht = l >> 4, ft = l & 15;
            const int h0 = ht * 4, f0 = ft * 4;
            float acc[4][4] = {{0.f}};
#pragma unroll
            for (int e0 = 0; e0 < 64; e0 += 4) {
                float4 mrow[4], wrow[4];
#pragma unroll
                for (int i = 0; i < 4; ++i) mrow[i] = *(const float4*)&sMeanP[h0 + i][e0];
#pragma unroll
                for (int j = 0; j < 4; ++j) wrow[j] = *(const float4*)&W[(e0 + j) * 64 + f0];
#pragma unroll
                for (int i = 0; i < 4; ++i) {
                    const float* mr = (const float*)&mrow[i];
#pragma unroll
                    for (int ee = 0; ee < 4; ++ee) {
                        const float* wr = (const float*)&wrow[ee];
#pragma unroll
                        for (int j = 0; j < 4; ++j)
                            acc[i][j] = fmaf(mr[ee], wr[j], acc[i][j]);
                    }
                }
            }
#pragma unroll
            for (int i = 0; i < 4; ++i)
                *(float4*)&sMW[h0 + i][f0] =
                    make_float4(acc[i][0], acc[i][1], acc[i][2], acc[i][3]);
        }
        LGKM0;

        // ---- Issue DMA prefetch for next batch (staging fully consumed in
        //      phase 1; W loads fully retired by their own waits in phase 2,
        //      so these 20 are the only outstanding VMEM until the stores).
        __builtin_amdgcn_sched_barrier(0);
        if (it + 1 < NB) {
            const size_t gbase = (size_t)(batch + 1) * (H * E);
#pragma unroll
            for (int k = 0; k < 4; ++k) {
                const int off = k * 256 + l * 4;
                dma16(o0 + gbase + off, &stg[0 * 1024 + k * 256]);
                dma16(o1 + gbase + off, &stg[1 * 1024 + k * 256]);
                dma16(o2 + gbase + off, &stg[2 * 1024 + k * 256]);
                dma16(o3 + gbase + off, &stg[3 * 1024 + k * 256]);
                dma16(mn + gbase + off, &stg[4 * 1024 + k * 256]);
            }
        }
        __builtin_amdgcn_sched_barrier(0);

        // ---- Phase 3: score[h][g] = sum_f mW[h][f]*main[g][f]
        //      written into sMeanP region (dead after phase 2), stride 68
        {
            const int hp = l >> 3, gp = l & 7;
            const int h0 = hp * 2, g0 = gp * 2;
            float sc00 = 0.f, sc01 = 0.f, sc10 = 0.f, sc11 = 0.f;
#pragma unroll
            for (int f0 = 0; f0 < 64; f0 += 4) {
                float4 a0 = *(const float4*)&sMW[h0][f0];
                float4 a1 = *(const float4*)&sMW[h0 + 1][f0];
                float4 b0 = *(const float4*)&sMainP[g0][f0];
                float4 b1 = *(const float4*)&sMainP[g0 + 1][f0];
                const float* pa0 = (const float*)&a0;
                const float* pa1 = (const float*)&a1;
                const float* pb0 = (const float*)&b0;
                const float* pb1 = (const float*)&b1;
#pragma unroll
                for (int q = 0; q < 4; ++q) {
                    sc00 = fmaf(pa0[q], pb0[q], sc00);
                    sc01 = fmaf(pa0[q], pb1[q], sc01);
                    sc10 = fmaf(pa1[q], pb0[q], sc10);
                    sc11 = fmaf(pa1[q], pb1[q], sc11);
                }
            }
            *(float2*)&sMeanP[h0][g0]     = make_float2(sc00, sc01);
            *(float2*)&sMeanP[h0 + 1][g0] = make_float2(sc10, sc11);
        }
        LGKM0;

        // ---- Phase 4: full-wave softmax; lane = h*4 + q, q owns 4 g's
        {
            const int h = l >> 2, q = l & 3;
            float4 sc = *(const float4*)&sMeanP[h][q * 4];
            float mx = fmaxf(fmaxf(sc.x, sc.y), fmaxf(sc.z, sc.w));
            mx = fmaxf(mx, __shfl_xor(mx, 1));
            mx = fmaxf(mx, __shfl_xor(mx, 2));
            float e0 = __expf(sc.x - mx), e1 = __expf(sc.y - mx);
            float e2 = __expf(sc.z - mx), e3 = __expf(sc.w - mx);
            float sum = (e0 + e1) + (e2 + e3);
            sum += __shfl_xor(sum, 1);
            sum += __shfl_xor(sum, 2);
            const float inv = 1.0f / sum;
            float4 a4 = make_float4(e0 * inv, e1 * inv, e2 * inv, e3 * inv);
            *(float4*)&sMeanP[h][q * 4] = a4;   // attn in place, stride 68
            *(float4*)(attn_out + (size_t)batch * (H * H) + l * 4) = a4;
        }
        LGKM0;

        // ---- Phase 5: context[h][e] = sum_g attn[h][g]*main[g][e]
        {
            const int ht = l >> 4, et = l & 15;
            const int h0 = ht * 4, e0c = et * 4;
            float acc[4][4] = {{0.f}};
#pragma unroll
            for (int g0 = 0; g0 < 16; g0 += 4) {
                float4 bv[4];
#pragma unroll
                for (int gg = 0; gg < 4; ++gg)
                    bv[gg] = *(const float4*)&sMainP[g0 + gg][e0c];
#pragma unroll
                for (int i = 0; i < 4; ++i) {
                    float4 av = *(const float4*)&sMeanP[h0 + i][g0];
                    const float* pa = (const float*)&av;
#pragma unroll
                    for (int gg = 0; gg < 4; ++gg) {
                        const float* pb = (const float*)&bv[gg];
#pragma unroll
                        for (int j = 0; j < 4; ++j)
                            acc[i][j] = fmaf(pa[gg], pb[j], acc[i][j]);
                    }
                }
            }
            float* cp = ctx_out + (size_t)batch * (H * E);
#pragma unroll
            for (int i = 0; i < 4; ++i)
                *(float4*)(cp + (h0 + i) * 64 + e0c) =
                    make_float4(acc[i][0], acc[i][1], acc[i][2], acc[i][3]);
        }
        LGKM0;   // phase-5 LDS reads retired before next phase-1 overwrites
    }
}

extern "C" void kernel_launch(void* const* d_in, const int* in_sizes, int n_in,
                              void* d_out, int out_size, void* d_ws, size_t ws_size,
                              hipStream_t stream) {
    const float* o0 = (const float*)d_in[0];
    const float* o1 = (const float*)d_in[1];
    const float* o2 = (const float*)d_in[2];
    const float* o3 = (const float*)d_in[3];
    const float* mn = (const float*)d_in[4];
    const float* W  = (const float*)d_in[5];
    float* ctx  = (float*)d_out;
    float* attn = ctx + (size_t)NBATCH * H * E;
    hipLaunchKernelGGL(ovo_kernel, dim3(NBLK), dim3(64), 0, stream,
                       o0, o1, o2, o3, mn, W, ctx, attn);
}

// Round 4
// 95.810 us; speedup vs baseline: 8.4406x; 1.2730x over previous
//
#include <hip/hip_runtime.h>

#define NBATCH 16384
#define H 16
#define E 64

// Cross-lane-through-LDS phase fence: drain LDS pipe, then stop the
// scheduler from hoisting later ops above it (rule #18).
#define LGKM0 do { asm volatile("s_waitcnt lgkmcnt(0)" ::: "memory"); \
                   __builtin_amdgcn_sched_barrier(0); } while (0)

// One wave (64 threads) per batch. 12 blocks/CU (LDS-limited: 12.75KB) =
// 3 waves/SIMD of TLP. Inputs go global->reg->padded LDS with immediate
// consumption (no cross-phase register liveness -> no spill). No
// __syncthreads (single wave) and no vmcnt drains: only lgkm fences at
// the 5 cross-lane LDS handoffs. All LDS tiles padded to stride 68 so
// every phase's read/write pattern is <=2-way bank aliased (free).
__global__ __launch_bounds__(64, 3) void ovo_kernel(
    const float* __restrict__ o0, const float* __restrict__ o1,
    const float* __restrict__ o2, const float* __restrict__ o3,
    const float* __restrict__ mn, const float* __restrict__ W,
    float* __restrict__ ctx_out, float* __restrict__ attn_out)
{
    __shared__ float sMeanP[H][68];  // mean; score/attn overlay after phase 2
    __shared__ float sMainP[H][68];  // main
    __shared__ float sMW[H][68];     // mean @ W

    const int l = threadIdx.x;
    const size_t base = (size_t)blockIdx.x * (H * E);

    // ---- Issue all 20 input loads (coalesced 1KB each); transient regs only.
    float4 ra[4], rb[4], rc[4], rd[4], rv[4];
#pragma unroll
    for (int k = 0; k < 4; ++k) {
        const int off = k * 256 + l * 4;
        ra[k] = *(const float4*)(o0 + base + off);
        rb[k] = *(const float4*)(o1 + base + off);
        rc[k] = *(const float4*)(o2 + base + off);
        rd[k] = *(const float4*)(o3 + base + off);
        rv[k] = *(const float4*)(mn + base + off);
    }

    // ---- Phase 1: mean -> sMeanP, main -> sMainP (padded writes)
#pragma unroll
    for (int k = 0; k < 4; ++k) {
        const int flat = k * 256 + l * 4;
        const int h = flat >> 6, e = flat & 63;
        float4 m4;
        m4.x = (ra[k].x + rb[k].x + rc[k].x + rd[k].x) * 0.25f;
        m4.y = (ra[k].y + rb[k].y + rc[k].y + rd[k].y) * 0.25f;
        m4.z = (ra[k].z + rb[k].z + rc[k].z + rd[k].z) * 0.25f;
        m4.w = (ra[k].w + rb[k].w + rc[k].w + rd[k].w) * 0.25f;
        *(float4*)&sMeanP[h][e] = m4;
        *(float4*)&sMainP[h][e] = rv[k];
    }
    LGKM0;

    // ---- Phase 2: mW[h][f] = sum_e mean[h][e] * W[e][f]   (4x4 tile/lane)
    {
        const int ht = l >> 4, ft = l & 15;
        const int h0 = ht * 4, f0 = ft * 4;
        float acc[4][4] = {{0.f}};
#pragma unroll
        for (int e0 = 0; e0 < 64; e0 += 4) {
            float4 mrow[4], wrow[4];
#pragma unroll
            for (int i = 0; i < 4; ++i) mrow[i] = *(const float4*)&sMeanP[h0 + i][e0];
#pragma unroll
            for (int j = 0; j < 4; ++j) wrow[j] = *(const float4*)&W[(e0 + j) * 64 + f0];
#pragma unroll
            for (int i = 0; i < 4; ++i) {
                const float* mr = (const float*)&mrow[i];
#pragma unroll
                for (int ee = 0; ee < 4; ++ee) {
                    const float* wr = (const float*)&wrow[ee];
#pragma unroll
                    for (int j = 0; j < 4; ++j)
                        acc[i][j] = fmaf(mr[ee], wr[j], acc[i][j]);
                }
            }
        }
#pragma unroll
        for (int i = 0; i < 4; ++i)
            *(float4*)&sMW[h0 + i][f0] =
                make_float4(acc[i][0], acc[i][1], acc[i][2], acc[i][3]);
    }
    LGKM0;

    // ---- Phase 3: score[h][g] = sum_f mW[h][f]*main[g][f]
    //      (2x2 tile/lane; score written into sMeanP overlay, stride 68)
    {
        const int hp = l >> 3, gp = l & 7;
        const int h0 = hp * 2, g0 = gp * 2;
        float sc00 = 0.f, sc01 = 0.f, sc10 = 0.f, sc11 = 0.f;
#pragma unroll
        for (int f0 = 0; f0 < 64; f0 += 4) {
            float4 a0 = *(const float4*)&sMW[h0][f0];
            float4 a1 = *(const float4*)&sMW[h0 + 1][f0];
            float4 b0 = *(const float4*)&sMainP[g0][f0];
            float4 b1 = *(const float4*)&sMainP[g0 + 1][f0];
            const float* pa0 = (const float*)&a0;
            const float* pa1 = (const float*)&a1;
            const float* pb0 = (const float*)&b0;
            const float* pb1 = (const float*)&b1;
#pragma unroll
            for (int q = 0; q < 4; ++q) {
                sc00 = fmaf(pa0[q], pb0[q], sc00);
                sc01 = fmaf(pa0[q], pb1[q], sc01);
                sc10 = fmaf(pa1[q], pb0[q], sc10);
                sc11 = fmaf(pa1[q], pb1[q], sc11);
            }
        }
        *(float2*)&sMeanP[h0][g0]     = make_float2(sc00, sc01);
        *(float2*)&sMeanP[h0 + 1][g0] = make_float2(sc10, sc11);
    }
    LGKM0;

    // ---- Phase 4: full-wave softmax; lane = h*4 + q, q owns 4 g's
    {
        const int h = l >> 2, q = l & 3;
        float4 sc = *(const float4*)&sMeanP[h][q * 4];
        float mx = fmaxf(fmaxf(sc.x, sc.y), fmaxf(sc.z, sc.w));
        mx = fmaxf(mx, __shfl_xor(mx, 1));
        mx = fmaxf(mx, __shfl_xor(mx, 2));
        float e0 = __expf(sc.x - mx), e1 = __expf(sc.y - mx);
        float e2 = __expf(sc.z - mx), e3 = __expf(sc.w - mx);
        float sum = (e0 + e1) + (e2 + e3);
        sum += __shfl_xor(sum, 1);
        sum += __shfl_xor(sum, 2);
        const float inv = 1.0f / sum;
        float4 a4 = make_float4(e0 * inv, e1 * inv, e2 * inv, e3 * inv);
        *(float4*)&sMeanP[h][q * 4] = a4;   // attn in place
        *(float4*)(attn_out + (size_t)blockIdx.x * (H * H) + l * 4) = a4;
    }
    LGKM0;

    // ---- Phase 5: context[h][e] = sum_g attn[h][g]*main[g][e] (4x4 tile)
    {
        const int ht = l >> 4, et = l & 15;
        const int h0 = ht * 4, e0c = et * 4;
        float acc[4][4] = {{0.f}};
#pragma unroll
        for (int g0 = 0; g0 < 16; g0 += 4) {
            float4 bv[4];
#pragma unroll
            for (int gg = 0; gg < 4; ++gg)
                bv[gg] = *(const float4*)&sMainP[g0 + gg][e0c];
#pragma unroll
            for (int i = 0; i < 4; ++i) {
                float4 av = *(const float4*)&sMeanP[h0 + i][g0];
                const float* pa = (const float*)&av;
#pragma unroll
                for (int gg = 0; gg < 4; ++gg) {
                    const float* pb = (const float*)&bv[gg];
#pragma unroll
                    for (int j = 0; j < 4; ++j)
                        acc[i][j] = fmaf(pa[gg], pb[j], acc[i][j]);
                }
            }
        }
        float* cp = ctx_out + base;
#pragma unroll
        for (int i = 0; i < 4; ++i)
            *(float4*)(cp + (h0 + i) * 64 + e0c) =
                make_float4(acc[i][0], acc[i][1], acc[i][2], acc[i][3]);
    }
}

extern "C" void kernel_launch(void* const* d_in, const int* in_sizes, int n_in,
                              void* d_out, int out_size, void* d_ws, size_t ws_size,
                              hipStream_t stream) {
    const float* o0 = (const float*)d_in[0];
    const float* o1 = (const float*)d_in[1];
    const float* o2 = (const float*)d_in[2];
    const float* o3 = (const float*)d_in[3];
    const float* mn = (const float*)d_in[4];
    const float* W  = (const float*)d_in[5];
    float* ctx  = (float*)d_out;
    float* attn = ctx + (size_t)NBATCH * H * E;
    hipLaunchKernelGGL(ovo_kernel, dim3(NBATCH), dim3(64), 0, stream,
                       o0, o1, o2, o3, mn, W, ctx, attn);
}